// Round 1
// baseline (4857.988 us; speedup 1.0000x reference)
//
#include <hip/hip_runtime.h>

#define E_CNT   32768
#define V_CNT   98304
#define D_      128
#define VOCAB_  2000
#define ITERS_  6
#define TE      32

__device__ __forceinline__ float sigmoid_f(float x) { return 1.0f / (1.0f + __expf(-x)); }
__device__ __forceinline__ float tanh_f(float x) {
    float ax = fabsf(x);
    float t = 1.0f - 2.0f / (__expf(2.0f * ax) + 1.0f);
    return copysignf(t, x);
}

// Detect whether target_mask is byte-packed (numpy bool) or int32.
// If int32 {0,1}: every 32-bit word <= 1. If bytes: some word has high bytes set.
__global__ void detect_mask_kernel(const unsigned int* __restrict__ m, int* __restrict__ flag) {
    int i = blockIdx.x * 256 + threadIdx.x;
    if (i < 4096 && m[i] > 1u) atomicOr(flag, 1);
}

// Build transposed+concatenated weights and fused biases.
// WvT[j][k], j in [0,512): j<384 -> Wih_v2e[k][j], else Whh_v2e[k][j-384]
// WeT[p][j][k], j in [0,256): j<128 -> Wih_e2v[p][k][j], else Whh_e2v[p][k][j-128]
__global__ void prep_kernel(
    const float* __restrict__ Wih_v2e, const float* __restrict__ Whh_v2e,
    const float* __restrict__ bih_v2e, const float* __restrict__ bhh_v2e,
    const float* __restrict__ Wih_e2v, const float* __restrict__ Whh_e2v,
    const float* __restrict__ bih_e2v, const float* __restrict__ bhh_e2v,
    float* __restrict__ WvT, float* __restrict__ WeT,
    float* __restrict__ bv, float* __restrict__ be)
{
    int idx = blockIdx.x * 256 + threadIdx.x;
    if (idx < 512 * 512) {
        int j = idx >> 9, k = idx & 511;
        WvT[idx] = (j < 384) ? Wih_v2e[k * 384 + j] : Whh_v2e[k * 128 + (j - 384)];
        return;
    }
    idx -= 512 * 512;
    if (idx < 3 * 256 * 512) {
        int p = idx >> 17, r = idx & 131071;
        int j = r >> 9, k = r & 511;
        WeT[idx] = (j < 128) ? Wih_e2v[(p * 512 + k) * 128 + j]
                             : Whh_e2v[(p * 512 + k) * 128 + (j - 128)];
        return;
    }
    idx -= 3 * 256 * 512;
    if (idx < 512) { bv[idx] = bih_v2e[idx] + bhh_v2e[idx]; return; }
    idx -= 512;
    if (idx < 1536) { be[idx] = bih_e2v[idx] + bhh_e2v[idx]; return; }
}

__global__ void init_state_kernel(const int* __restrict__ x_v,
    const float* __restrict__ emb,
    const float* __restrict__ eiw, const float* __restrict__ eib,
    float* __restrict__ h_v, float* __restrict__ c_v,
    float* __restrict__ h_e, float* __restrict__ c_e)
{
    int idx = blockIdx.x * 256 + threadIdx.x;   // < V_CNT * D_
    int v = idx >> 7, d = idx & 127;
    int id = x_v[v];
    if (id < 0 || id > VOCAB_) id = VOCAB_;
    h_v[idx] = emb[id * D_ + d];
    c_v[idx] = 0.0f;
    if (idx < E_CNT * D_) {
        h_e[idx] = eiw[d] + eib[d];
        c_e[idx] = 0.0f;
    }
}

// vertex->edge LSTM step. 256 threads, TE=32 edges per block.
// Thread owns 8 edges x 8 gate-slots: k = s*64 + kg  (s=0..7, kg=tid&63)
// -> s=0,1:i  s=2,3:f  s=4,5:g  s=6,7:o  for d=kg and d=kg+64 : full LSTM cell in-register.
__global__ __launch_bounds__(256) void v2e_kernel(
    const float* __restrict__ h_v, float* __restrict__ h_e, float* __restrict__ c_e,
    const float* __restrict__ WvT, const float* __restrict__ bv)
{
    __shared__ float X[TE][512];
    const int tid = threadIdx.x;
    const int e0 = blockIdx.x * TE;
    for (int idx = tid; idx < TE * 384; idx += 256) {
        int e = idx / 384;
        int j = idx - e * 384;
        X[e][j] = h_v[e0 * 384 + idx];
    }
    for (int idx = tid; idx < TE * 128; idx += 256) {
        X[idx >> 7][384 + (idx & 127)] = h_e[e0 * 128 + idx];
    }
    __syncthreads();

    const int kg = tid & 63;
    const int er = (tid >> 6) * 8;

    float acc[8][8];
    #pragma unroll
    for (int i = 0; i < 8; ++i)
        #pragma unroll
        for (int s = 0; s < 8; ++s) acc[i][s] = 0.0f;

    for (int j = 0; j < 512; j += 4) {
        float4 xv[8];
        #pragma unroll
        for (int i = 0; i < 8; ++i) xv[i] = *(const float4*)&X[er + i][j];
        #pragma unroll
        for (int r = 0; r < 4; ++r) {
            float w[8];
            #pragma unroll
            for (int s = 0; s < 8; ++s) w[s] = WvT[(j + r) * 512 + s * 64 + kg];
            #pragma unroll
            for (int i = 0; i < 8; ++i) {
                const float x = (&xv[i].x)[r];
                #pragma unroll
                for (int s = 0; s < 8; ++s) acc[i][s] = fmaf(x, w[s], acc[i][s]);
            }
        }
    }

    const float bi0 = bv[kg],       bi1 = bv[kg + 64];
    const float bf0 = bv[kg + 128], bf1 = bv[kg + 192];
    const float bg0 = bv[kg + 256], bg1 = bv[kg + 320];
    const float bo0 = bv[kg + 384], bo1 = bv[kg + 448];
    #pragma unroll
    for (int i = 0; i < 8; ++i) {
        const int e = e0 + er + i;
        {
            float gi = sigmoid_f(acc[i][0] + bi0);
            float gf = sigmoid_f(acc[i][2] + bf0);
            float gg = tanh_f(acc[i][4] + bg0);
            float go = sigmoid_f(acc[i][6] + bo0);
            float cn = gf * c_e[e * D_ + kg] + gi * gg;
            c_e[e * D_ + kg] = cn;
            h_e[e * D_ + kg] = go * tanh_f(cn);
        }
        {
            float gi = sigmoid_f(acc[i][1] + bi1);
            float gf = sigmoid_f(acc[i][3] + bf1);
            float gg = tanh_f(acc[i][5] + bg1);
            float go = sigmoid_f(acc[i][7] + bo1);
            float cn = gf * c_e[e * D_ + kg + 64] + gi * gg;
            c_e[e * D_ + kg + 64] = cn;
            h_e[e * D_ + kg + 64] = go * tanh_f(cn);
        }
    }
}

// edge->vertex: 3 position-specific LSTMs, masked update of h_v/c_v.
__global__ __launch_bounds__(256) void e2v_kernel(
    const float* __restrict__ h_e, float* __restrict__ h_v, float* __restrict__ c_v,
    const float* __restrict__ WeT, const float* __restrict__ be,
    const void* __restrict__ mask, const int* __restrict__ flagp)
{
    __shared__ float Xe[TE][128];
    __shared__ float Xv[TE][128];
    const int tid = threadIdx.x;
    const int e0 = blockIdx.x * TE;
    const int isByte = *flagp;
    for (int idx = tid; idx < TE * 128; idx += 256)
        Xe[idx >> 7][idx & 127] = h_e[e0 * 128 + idx];

    const int kg = tid & 63;
    const int er = (tid >> 6) * 8;

    for (int p = 0; p < 3; ++p) {
        __syncthreads();
        for (int idx = tid; idx < TE * 128; idx += 256) {
            int e = idx >> 7, d = idx & 127;
            Xv[e][d] = h_v[((e0 + e) * 3 + p) * D_ + d];
        }
        __syncthreads();

        const float* Wp = WeT + p * (256 * 512);
        float acc[8][8];
        #pragma unroll
        for (int i = 0; i < 8; ++i)
            #pragma unroll
            for (int s = 0; s < 8; ++s) acc[i][s] = 0.0f;

        #pragma unroll
        for (int half = 0; half < 2; ++half) {
            const float (*Xs)[128] = half ? Xv : Xe;
            const float* Wh = Wp + half * (128 * 512);
            for (int j = 0; j < 128; j += 4) {
                float4 xv[8];
                #pragma unroll
                for (int i = 0; i < 8; ++i) xv[i] = *(const float4*)&Xs[er + i][j];
                #pragma unroll
                for (int r = 0; r < 4; ++r) {
                    float w[8];
                    #pragma unroll
                    for (int s = 0; s < 8; ++s) w[s] = Wh[(j + r) * 512 + s * 64 + kg];
                    #pragma unroll
                    for (int i = 0; i < 8; ++i) {
                        const float x = (&xv[i].x)[r];
                        #pragma unroll
                        for (int s = 0; s < 8; ++s) acc[i][s] = fmaf(x, w[s], acc[i][s]);
                    }
                }
            }
        }

        const float bi0 = be[p * 512 + kg],       bi1 = be[p * 512 + kg + 64];
        const float bf0 = be[p * 512 + kg + 128], bf1 = be[p * 512 + kg + 192];
        const float bg0 = be[p * 512 + kg + 256], bg1 = be[p * 512 + kg + 320];
        const float bo0 = be[p * 512 + kg + 384], bo1 = be[p * 512 + kg + 448];
        #pragma unroll
        for (int i = 0; i < 8; ++i) {
            const int v = (e0 + er + i) * 3 + p;
            bool m = isByte ? (((const unsigned char*)mask)[v] != 0)
                            : (((const int*)mask)[v] != 0);
            if (!m) continue;
            {
                float gi = sigmoid_f(acc[i][0] + bi0);
                float gf = sigmoid_f(acc[i][2] + bf0);
                float gg = tanh_f(acc[i][4] + bg0);
                float go = sigmoid_f(acc[i][6] + bo0);
                float cn = gf * c_v[v * D_ + kg] + gi * gg;
                c_v[v * D_ + kg] = cn;
                h_v[v * D_ + kg] = go * tanh_f(cn);
            }
            {
                float gi = sigmoid_f(acc[i][1] + bi1);
                float gf = sigmoid_f(acc[i][3] + bf1);
                float gg = tanh_f(acc[i][5] + bg1);
                float go = sigmoid_f(acc[i][7] + bo1);
                float cn = gf * c_v[v * D_ + kg + 64] + gi * gg;
                c_v[v * D_ + kg + 64] = cn;
                h_v[v * D_ + kg + 64] = go * tanh_f(cn);
            }
        }
    }
}

// logits[98304,2000] = h_v @ out_w^T + out_b.  Block: 128 rows x 128 cols, 512 thr,
// thread: 8 rows x 4 cols.  h rows staged in LDS (broadcast reads), w via float4 global (L1/L2).
__global__ __launch_bounds__(512) void proj_kernel(
    const float* __restrict__ h_v, const float* __restrict__ out_w,
    const float* __restrict__ out_b, float* __restrict__ out)
{
    __shared__ float hs[128][128];
    const int tid = threadIdx.x;
    const int row0 = blockIdx.x * 128;
    const int col0 = blockIdx.y * 128;
    for (int idx = tid; idx < 16384; idx += 512)
        hs[idx >> 7][idx & 127] = h_v[row0 * 128 + idx];
    __syncthreads();

    const int cg = tid & 31;
    const int rg = tid >> 5;
    const int c0 = col0 + cg * 4;
    const int r0 = rg * 8;
    if (c0 >= VOCAB_) return;   // after the only barrier

    float acc[8][4];
    #pragma unroll
    for (int i = 0; i < 8; ++i)
        #pragma unroll
        for (int c = 0; c < 4; ++c) acc[i][c] = 0.0f;

    for (int k = 0; k < 128; k += 4) {
        float4 wv[4];
        #pragma unroll
        for (int c = 0; c < 4; ++c)
            wv[c] = *(const float4*)&out_w[(c0 + c) * 128 + k];
        #pragma unroll
        for (int i = 0; i < 8; ++i) {
            float4 x = *(const float4*)&hs[r0 + i][k];
            #pragma unroll
            for (int c = 0; c < 4; ++c)
                acc[i][c] += x.x * wv[c].x + x.y * wv[c].y + x.z * wv[c].z + x.w * wv[c].w;
        }
    }

    const float b0 = out_b[c0], b1 = out_b[c0 + 1], b2 = out_b[c0 + 2], b3 = out_b[c0 + 3];
    #pragma unroll
    for (int i = 0; i < 8; ++i) {
        float4 o = make_float4(acc[i][0] + b0, acc[i][1] + b1, acc[i][2] + b2, acc[i][3] + b3);
        *(float4*)&out[(size_t)(row0 + r0 + i) * VOCAB_ + c0] = o;
    }
}

extern "C" void kernel_launch(void* const* d_in, const int* in_sizes, int n_in,
                              void* d_out, int out_size, void* d_ws, size_t ws_size,
                              hipStream_t stream)
{
    const int*   x_v     = (const int*)  d_in[0];
    const void*  mask    = d_in[1];
    const float* emb     = (const float*)d_in[2];
    const float* eiw     = (const float*)d_in[3];
    const float* eib     = (const float*)d_in[4];
    const float* Wih_v2e = (const float*)d_in[5];
    const float* Whh_v2e = (const float*)d_in[6];
    const float* bih_v2e = (const float*)d_in[7];
    const float* bhh_v2e = (const float*)d_in[8];
    const float* Wih_e2v = (const float*)d_in[9];
    const float* Whh_e2v = (const float*)d_in[10];
    const float* bih_e2v = (const float*)d_in[11];
    const float* bhh_e2v = (const float*)d_in[12];
    const float* out_w   = (const float*)d_in[13];
    const float* out_b   = (const float*)d_in[14];
    float* out = (float*)d_out;

    float* ws  = (float*)d_ws;
    float* h_v = ws;                          // 12582912 floats
    float* c_v = h_v + 12582912;              // 12582912
    float* h_e = c_v + 12582912;              // 4194304
    float* c_e = h_e + 4194304;               // 4194304
    float* WvT = c_e + 4194304;               // 262144
    float* WeT = WvT + 262144;                // 393216
    float* bv  = WeT + 393216;                // 512
    float* be  = bv + 512;                    // 1536
    int*   flag = (int*)(be + 1536);

    hipMemsetAsync(flag, 0, sizeof(int), stream);
    detect_mask_kernel<<<16, 256, 0, stream>>>((const unsigned int*)mask, flag);
    prep_kernel<<<2568, 256, 0, stream>>>(Wih_v2e, Whh_v2e, bih_v2e, bhh_v2e,
                                          Wih_e2v, Whh_e2v, bih_e2v, bhh_e2v,
                                          WvT, WeT, bv, be);
    init_state_kernel<<<49152, 256, 0, stream>>>(x_v, emb, eiw, eib, h_v, c_v, h_e, c_e);

    for (int it = 0; it < ITERS_; ++it) {
        v2e_kernel<<<E_CNT / TE, 256, 0, stream>>>(h_v, h_e, c_e, WvT, bv);
        e2v_kernel<<<E_CNT / TE, 256, 0, stream>>>(h_e, h_v, c_v, WeT, be, mask, flag);
    }

    proj_kernel<<<dim3(V_CNT / 128, 16), 512, 0, stream>>>(h_v, out_w, out_b, out);
}

// Round 2
// 2840.338 us; speedup vs baseline: 1.7104x; 1.7104x over previous
//
#include <hip/hip_runtime.h>

#define E_CNT 32768
#define V_CNT 98304
#define D_ 128
#define VOCAB_ 2000
#define ITERS_ 6

typedef unsigned short u16;
typedef __attribute__((ext_vector_type(8))) short bf16x8;
typedef __attribute__((ext_vector_type(8))) unsigned short u16x8;
typedef __attribute__((ext_vector_type(4))) float f32x4;

__device__ __forceinline__ f32x4 MF(bf16x8 a, bf16x8 b, f32x4 c) {
    return __builtin_amdgcn_mfma_f32_16x16x32_bf16(a, b, c, 0, 0, 0);
}
__device__ __forceinline__ bf16x8 ld8(const u16* p) { return *reinterpret_cast<const bf16x8*>(p); }

__device__ __forceinline__ u16 f2bf(float x) {
    unsigned u = __float_as_uint(x);
    return (u16)((u + 0x7FFFu + ((u >> 16) & 1u)) >> 16);
}
__device__ __forceinline__ float bf2f(u16 h) { return __uint_as_float(((unsigned)h) << 16); }
__device__ __forceinline__ float sigmoid_f(float x) { return 1.0f / (1.0f + __expf(-x)); }
__device__ __forceinline__ float tanh_f(float x) {
    float ax = fabsf(x);
    float t = 1.0f - 2.0f / (__expf(2.0f * ax) + 1.0f);
    return copysignf(t, x);
}

// mask dtype detection: int32 {0,1} words are <=1; byte-packed bools produce big words.
__global__ void detect_mask_kernel(const unsigned int* __restrict__ m, int* __restrict__ flag) {
    int i = blockIdx.x * 256 + threadIdx.x;
    if (i < 4096 && m[i] > 1u) atomicOr(flag, 1);
}

// Pack weights into MFMA fragment order (bf16 hi/lo split).
// WvF: [nt(32)][kk(16)][lane(64)][8]   j = nt*16+(l&15), k = kk*32+(l>>4)*8+r,  k<384 -> Wih_v2e, else Whh_v2e
// WeF: [p(3)][nt(32)][kk(8)][64][8]    k<128 -> Wih_e2v[p], else Whh_e2v[p]
// OwF: [nt(125)][kk(4)][64][8]         out_w
__global__ void prep_kernel(
    const float* __restrict__ Wih_v2e, const float* __restrict__ Whh_v2e,
    const float* __restrict__ bih_v2e, const float* __restrict__ bhh_v2e,
    const float* __restrict__ Wih_e2v, const float* __restrict__ Whh_e2v,
    const float* __restrict__ bih_e2v, const float* __restrict__ bhh_e2v,
    const float* __restrict__ out_w,
    u16* __restrict__ WvFh, u16* __restrict__ WvFl,
    u16* __restrict__ WeFh, u16* __restrict__ WeFl,
    u16* __restrict__ OwFh, u16* __restrict__ OwFl,
    float* __restrict__ bv, float* __restrict__ be)
{
    int idx = blockIdx.x * 256 + threadIdx.x;
    if (idx < 262144) {
        const int r = idx & 7, l = (idx >> 3) & 63, t = idx >> 9;
        const int kk = t & 15, nt = t >> 4;
        const int j = nt * 16 + (l & 15);
        const int k = kk * 32 + (l >> 4) * 8 + r;
        const float w = (k < 384) ? Wih_v2e[j * 384 + k] : Whh_v2e[j * 128 + (k - 384)];
        const u16 h = f2bf(w);
        WvFh[idx] = h; WvFl[idx] = f2bf(w - bf2f(h));
        return;
    }
    idx -= 262144;
    if (idx < 393216) {
        const int r = idx & 7, l = (idx >> 3) & 63, t = idx >> 9;  // t < 768
        const int kk = t & 7, nt = (t >> 3) & 31, p = t >> 8;
        const int j = nt * 16 + (l & 15);
        const int k = kk * 32 + (l >> 4) * 8 + r;
        const float w = (k < 128) ? Wih_e2v[(p * 512 + j) * 128 + k]
                                  : Whh_e2v[(p * 512 + j) * 128 + (k - 128)];
        const u16 h = f2bf(w);
        WeFh[idx] = h; WeFl[idx] = f2bf(w - bf2f(h));
        return;
    }
    idx -= 393216;
    if (idx < 256000) {
        const int r = idx & 7, l = (idx >> 3) & 63, t = idx >> 9;  // t < 500
        const int kk = t & 3, nt = t >> 2;
        const int j = nt * 16 + (l & 15);
        const int k = kk * 32 + (l >> 4) * 8 + r;
        const float w = out_w[j * 128 + k];
        const u16 h = f2bf(w);
        OwFh[idx] = h; OwFl[idx] = f2bf(w - bf2f(h));
        return;
    }
    idx -= 256000;
    if (idx < 512) { bv[idx] = bih_v2e[idx] + bhh_v2e[idx]; return; }
    idx -= 512;
    if (idx < 1536) { be[idx] = bih_e2v[idx] + bhh_e2v[idx]; return; }
}

// State init: h_v from embedding (bf16 hi/lo pair), h_e from edge_init, c = 0.
__global__ void init_kernel(const int* __restrict__ x_v,
    const float* __restrict__ emb, const float* __restrict__ eiw, const float* __restrict__ eib,
    u16* __restrict__ hvh, u16* __restrict__ hvl, float* __restrict__ c_v,
    u16* __restrict__ heh, u16* __restrict__ hel, float* __restrict__ c_e)
{
    int idx = blockIdx.x * 256 + threadIdx.x;
    const float4 z = make_float4(0.f, 0.f, 0.f, 0.f);
    if (idx < V_CNT * 16) {
        const int v = idx >> 4, g = idx & 15;
        int id = x_v[v];
        if (id < 0 || id > VOCAB_) id = VOCAB_;
        const float* s = emb + id * D_ + g * 8;
        float4 a = *(const float4*)(s);
        float4 b = *(const float4*)(s + 4);
        float xs[8] = {a.x, a.y, a.z, a.w, b.x, b.y, b.z, b.w};
        u16x8 H, L;
        #pragma unroll
        for (int j = 0; j < 8; ++j) {
            H[j] = f2bf(xs[j]); L[j] = f2bf(xs[j] - bf2f(H[j]));
        }
        *(u16x8*)(hvh + idx * 8) = H;
        *(u16x8*)(hvl + idx * 8) = L;
        *(float4*)(c_v + idx * 8) = z;
        *(float4*)(c_v + idx * 8 + 4) = z;
        return;
    }
    idx -= V_CNT * 16;
    if (idx < E_CNT * 16) {
        const int g = idx & 15;
        u16x8 H, L;
        #pragma unroll
        for (int j = 0; j < 8; ++j) {
            const float x = eiw[g * 8 + j] + eib[g * 8 + j];
            H[j] = f2bf(x); L[j] = f2bf(x - bf2f(H[j]));
        }
        *(u16x8*)(heh + idx * 8) = H;
        *(u16x8*)(hel + idx * 8) = L;
        *(float4*)(c_e + idx * 8) = z;
        *(float4*)(c_e + idx * 8 + 4) = z;
    }
}

// vertex->edge. Wave unit: 64 edges (4 M-tiles) x gate-slice c (d = c*16 + lr).
// gates i/f/g/o live at N-tiles {c, 8+c, 16+c, 24+c} -> same lane owns matched gates.
__global__ __launch_bounds__(256) void v2e_kernel(
    const u16* __restrict__ hvh, const u16* __restrict__ hvl,
    const u16* __restrict__ heih, const u16* __restrict__ heil,
    u16* __restrict__ heoh, u16* __restrict__ heol,
    float* __restrict__ c_e,
    const u16* __restrict__ WFh, const u16* __restrict__ WFl,
    const float* __restrict__ bv)
{
    const int tid = threadIdx.x;
    const int l = tid & 63;
    const int wid = blockIdx.x * 4 + (tid >> 6);
    const int e0 = (wid >> 3) * 64;
    const int c = wid & 7;
    const int lr = l & 15, lk = l >> 4;

    f32x4 acc[4][4];
    #pragma unroll
    for (int mt = 0; mt < 4; ++mt)
        #pragma unroll
        for (int g = 0; g < 4; ++g) acc[mt][g] = (f32x4)0.0f;

    int ar[4];
    #pragma unroll
    for (int mt = 0; mt < 4; ++mt) ar[mt] = e0 + mt * 16 + lr;

#define GEMM_STEP(AH, AL, FBASE)                                         \
    { _Pragma("unroll")                                                  \
      for (int g = 0; g < 4; ++g) {                                      \
          const int fb = (FBASE);                                        \
          bf16x8 Bh = ld8(WFh + fb), Bl = ld8(WFl + fb);                 \
          _Pragma("unroll")                                              \
          for (int mt = 0; mt < 4; ++mt) {                               \
              acc[mt][g] = MF(AH[mt], Bh, acc[mt][g]);                   \
              acc[mt][g] = MF(AH[mt], Bl, acc[mt][g]);                   \
              acc[mt][g] = MF(AL[mt], Bh, acc[mt][g]);                   \
          }                                                              \
      } }

    for (int kk = 0; kk < 12; ++kk) {
        const int k0 = kk * 32 + lk * 8;
        bf16x8 Ah[4], Al[4];
        #pragma unroll
        for (int mt = 0; mt < 4; ++mt) {
            const int off = ar[mt] * 384 + k0;
            Ah[mt] = ld8(hvh + off); Al[mt] = ld8(hvl + off);
        }
        GEMM_STEP(Ah, Al, (((g * 8 + c) * 16 + kk) * 64 + l) * 8)
    }
    for (int kk = 12; kk < 16; ++kk) {
        const int k0 = (kk - 12) * 32 + lk * 8;
        bf16x8 Ah[4], Al[4];
        #pragma unroll
        for (int mt = 0; mt < 4; ++mt) {
            const int off = ar[mt] * D_ + k0;
            Ah[mt] = ld8(heih + off); Al[mt] = ld8(heil + off);
        }
        GEMM_STEP(Ah, Al, (((g * 8 + c) * 16 + kk) * 64 + l) * 8)
    }

    const int d = c * 16 + lr;
    const float bi = bv[d], bff = bv[128 + d], bg = bv[256 + d], bo = bv[384 + d];
    #pragma unroll
    for (int mt = 0; mt < 4; ++mt) {
        #pragma unroll
        for (int r = 0; r < 4; ++r) {
            const int e = e0 + mt * 16 + lk * 4 + r;
            const int off = e * D_ + d;
            float gi = sigmoid_f(acc[mt][0][r] + bi);
            float gf = sigmoid_f(acc[mt][1][r] + bff);
            float gg = tanh_f(acc[mt][2][r] + bg);
            float go = sigmoid_f(acc[mt][3][r] + bo);
            float cn = gf * c_e[off] + gi * gg;
            c_e[off] = cn;
            float hn = go * tanh_f(cn);
            u16 hh = f2bf(hn);
            heoh[off] = hh;
            heol[off] = f2bf(hn - bf2f(hh));
        }
    }
}

// edge->vertex: 3 position LSTMs. Reads h_v(in)/h_e, writes h_v(out) (ping-pong), masked.
__global__ __launch_bounds__(256) void e2v_kernel(
    const u16* __restrict__ heh, const u16* __restrict__ hel,
    const u16* __restrict__ hvih, const u16* __restrict__ hvil,
    u16* __restrict__ hvoh, u16* __restrict__ hvol,
    float* __restrict__ c_v,
    const u16* __restrict__ WFh, const u16* __restrict__ WFl,
    const float* __restrict__ be,
    const void* __restrict__ mask, const int* __restrict__ flagp)
{
    const int tid = threadIdx.x;
    const int l = tid & 63;
    const int wid = blockIdx.x * 4 + (tid >> 6);
    const int e0 = (wid >> 3) * 64;
    const int c = wid & 7;
    const int lr = l & 15, lk = l >> 4;
    const int isByte = *flagp;

    for (int p = 0; p < 3; ++p) {
        f32x4 acc[4][4];
        #pragma unroll
        for (int mt = 0; mt < 4; ++mt)
            #pragma unroll
            for (int g = 0; g < 4; ++g) acc[mt][g] = (f32x4)0.0f;

        for (int kk = 0; kk < 4; ++kk) {
            const int k0 = kk * 32 + lk * 8;
            bf16x8 Ah[4], Al[4];
            #pragma unroll
            for (int mt = 0; mt < 4; ++mt) {
                const int off = (e0 + mt * 16 + lr) * D_ + k0;
                Ah[mt] = ld8(heh + off); Al[mt] = ld8(hel + off);
            }
            GEMM_STEP(Ah, Al, ((((p * 32) + (g * 8 + c)) * 8 + kk) * 64 + l) * 8)
        }
        for (int kk = 4; kk < 8; ++kk) {
            const int k0 = (kk - 4) * 32 + lk * 8;
            bf16x8 Ah[4], Al[4];
            #pragma unroll
            for (int mt = 0; mt < 4; ++mt) {
                const int off = ((e0 + mt * 16 + lr) * 3 + p) * D_ + k0;
                Ah[mt] = ld8(hvih + off); Al[mt] = ld8(hvil + off);
            }
            GEMM_STEP(Ah, Al, ((((p * 32) + (g * 8 + c)) * 8 + kk) * 64 + l) * 8)
        }

        const int d = c * 16 + lr;
        const float bi = be[p * 512 + d], bff = be[p * 512 + 128 + d];
        const float bg = be[p * 512 + 256 + d], bo = be[p * 512 + 384 + d];
        #pragma unroll
        for (int mt = 0; mt < 4; ++mt) {
            #pragma unroll
            for (int r = 0; r < 4; ++r) {
                const int e = e0 + mt * 16 + lk * 4 + r;
                const int v = e * 3 + p;
                const int off = v * D_ + d;
                const bool m = isByte ? (((const unsigned char*)mask)[v] != 0)
                                      : (((const int*)mask)[v] != 0);
                if (m) {
                    float gi = sigmoid_f(acc[mt][0][r] + bi);
                    float gf = sigmoid_f(acc[mt][1][r] + bff);
                    float gg = tanh_f(acc[mt][2][r] + bg);
                    float go = sigmoid_f(acc[mt][3][r] + bo);
                    float cn = gf * c_v[off] + gi * gg;
                    c_v[off] = cn;
                    float hn = go * tanh_f(cn);
                    u16 hh = f2bf(hn);
                    hvoh[off] = hh;
                    hvol[off] = f2bf(hn - bf2f(hh));
                } else {
                    hvoh[off] = hvih[off];
                    hvol[off] = hvil[off];
                }
            }
        }
    }
}

// logits = h_v @ out_w^T + out_b.  Wave: 32 rows in-register, loops 125 N-tiles.
__global__ __launch_bounds__(256) void proj_kernel(
    const u16* __restrict__ hvh, const u16* __restrict__ hvl,
    const u16* __restrict__ WFh, const u16* __restrict__ WFl,
    const float* __restrict__ out_b, float* __restrict__ out)
{
    const int tid = threadIdx.x, l = tid & 63;
    const int wid = blockIdx.x * 4 + (tid >> 6);   // 0..3071
    const int r0 = wid * 32;
    const int lr = l & 15, lk = l >> 4;

    bf16x8 Ah[2][4], Al[2][4];
    #pragma unroll
    for (int mt = 0; mt < 2; ++mt)
        #pragma unroll
        for (int kk = 0; kk < 4; ++kk) {
            const int off = (r0 + mt * 16 + lr) * D_ + kk * 32 + lk * 8;
            Ah[mt][kk] = ld8(hvh + off);
            Al[mt][kk] = ld8(hvl + off);
        }

    for (int nt = 0; nt < 125; ++nt) {
        f32x4 a0 = (f32x4)0.0f, a1 = (f32x4)0.0f;
        #pragma unroll
        for (int kk = 0; kk < 4; ++kk) {
            const int fb = ((nt * 4 + kk) * 64 + l) * 8;
            bf16x8 Bh = ld8(WFh + fb), Bl = ld8(WFl + fb);
            a0 = MF(Ah[0][kk], Bh, a0); a0 = MF(Ah[0][kk], Bl, a0); a0 = MF(Al[0][kk], Bh, a0);
            a1 = MF(Ah[1][kk], Bh, a1); a1 = MF(Ah[1][kk], Bl, a1); a1 = MF(Al[1][kk], Bh, a1);
        }
        const int n = nt * 16 + lr;
        const float bb = out_b[n];
        #pragma unroll
        for (int r = 0; r < 4; ++r) {
            const size_t row = (size_t)(r0 + lk * 4 + r);
            out[row * VOCAB_ + n] = a0[r] + bb;
            out[(row + 16) * VOCAB_ + n] = a1[r] + bb;
        }
    }
}

extern "C" void kernel_launch(void* const* d_in, const int* in_sizes, int n_in,
                              void* d_out, int out_size, void* d_ws, size_t ws_size,
                              hipStream_t stream)
{
    const int*   x_v     = (const int*)  d_in[0];
    const void*  mask    = d_in[1];
    const float* emb     = (const float*)d_in[2];
    const float* eiw     = (const float*)d_in[3];
    const float* eib     = (const float*)d_in[4];
    const float* Wih_v2e = (const float*)d_in[5];
    const float* Whh_v2e = (const float*)d_in[6];
    const float* bih_v2e = (const float*)d_in[7];
    const float* bhh_v2e = (const float*)d_in[8];
    const float* Wih_e2v = (const float*)d_in[9];
    const float* Whh_e2v = (const float*)d_in[10];
    const float* bih_e2v = (const float*)d_in[11];
    const float* bhh_e2v = (const float*)d_in[12];
    const float* out_w   = (const float*)d_in[13];
    const float* out_b   = (const float*)d_in[14];
    float* out = (float*)d_out;

    // d_ws carve (~71 MB)
    char* ws = (char*)d_ws;
    u16* hvAh = (u16*)(ws);
    u16* hvAl = (u16*)(ws + 25165824);
    u16* heAh = (u16*)(ws + 50331648);
    u16* heAl = (u16*)(ws + 58720256);
    u16* WvFh = (u16*)(ws + 67108864);
    u16* WvFl = (u16*)(ws + 67633152);
    u16* WeFh = (u16*)(ws + 68157440);
    u16* WeFl = (u16*)(ws + 68943872);
    u16* OwFh = (u16*)(ws + 69730304);
    u16* OwFl = (u16*)(ws + 70242304);
    float* bv = (float*)(ws + 70754304);
    float* be = (float*)(ws + 70756352);
    int* flag = (int*)(ws + 70762496);

    // d_out head carve (128 MB, all dead before proj_kernel overwrites)
    char* ob = (char*)d_out;
    u16*   hvBh = (u16*)(ob);
    u16*   hvBl = (u16*)(ob + 25165824);
    float* c_v  = (float*)(ob + 50331648);
    u16*   heBh = (u16*)(ob + 100663296);
    u16*   heBl = (u16*)(ob + 109051904);
    float* c_e  = (float*)(ob + 117440512);

    hipMemsetAsync(flag, 0, 4, stream);
    detect_mask_kernel<<<16, 256, 0, stream>>>((const unsigned int*)mask, flag);
    prep_kernel<<<3568, 256, 0, stream>>>(Wih_v2e, Whh_v2e, bih_v2e, bhh_v2e,
                                          Wih_e2v, Whh_e2v, bih_e2v, bhh_e2v, out_w,
                                          WvFh, WvFl, WeFh, WeFl, OwFh, OwFl, bv, be);
    init_kernel<<<8192, 256, 0, stream>>>(x_v, emb, eiw, eib,
                                          hvAh, hvAl, c_v, heAh, heAl, c_e);

    for (int it = 0; it < ITERS_; ++it) {
        const u16 *hin_h  = (it & 1) ? hvBh : hvAh, *hin_l  = (it & 1) ? hvBl : hvAl;
        u16       *hout_h = (it & 1) ? hvAh : hvBh, *hout_l = (it & 1) ? hvAl : hvBl;
        const u16 *hein_h = (it & 1) ? heBh : heAh, *hein_l = (it & 1) ? heBl : heAl;
        u16       *heout_h = (it & 1) ? heAh : heBh, *heout_l = (it & 1) ? heAl : heBl;
        v2e_kernel<<<1024, 256, 0, stream>>>(hin_h, hin_l, hein_h, hein_l,
                                             heout_h, heout_l, c_e, WvFh, WvFl, bv);
        e2v_kernel<<<1024, 256, 0, stream>>>(heout_h, heout_l, hin_h, hin_l,
                                             hout_h, hout_l, c_v, WeFh, WeFl, be, mask, flag);
    }

    proj_kernel<<<768, 256, 0, stream>>>(hvAh, hvAl, OwFh, OwFl, out_b, out);
}

// Round 3
// 2073.547 us; speedup vs baseline: 2.3428x; 1.3698x over previous
//
#include <hip/hip_runtime.h>

#define E_CNT 32768
#define V_CNT 98304
#define D_ 128
#define VOCAB_ 2000
#define ITERS_ 6

typedef unsigned short u16;
typedef __attribute__((ext_vector_type(8))) short bf16x8;
typedef __attribute__((ext_vector_type(8))) unsigned short u16x8;
typedef __attribute__((ext_vector_type(4))) float f32x4;

__device__ __forceinline__ f32x4 MF(bf16x8 a, bf16x8 b, f32x4 c) {
    return __builtin_amdgcn_mfma_f32_16x16x32_bf16(a, b, c, 0, 0, 0);
}
__device__ __forceinline__ bf16x8 ld8(const u16* p) { return *reinterpret_cast<const bf16x8*>(p); }

__device__ __forceinline__ u16 f2bf(float x) {
    unsigned u = __float_as_uint(x);
    return (u16)((u + 0x7FFFu + ((u >> 16) & 1u)) >> 16);
}
__device__ __forceinline__ float bf2f(u16 h) { return __uint_as_float(((unsigned)h) << 16); }
__device__ __forceinline__ float sigmoid_f(float x) { return 1.0f / (1.0f + __expf(-x)); }
__device__ __forceinline__ float tanh_f(float x) {
    float ax = fabsf(x);
    float t = 1.0f - 2.0f / (__expf(2.0f * ax) + 1.0f);
    return copysignf(t, x);
}

// LDS swizzle (u16-unit index): XOR (row&7)<<3 u16s == <<4 bytes.
// Breaks the row-stride ≡ 0 (mod 128B) 16-way bank conflict on ds_read_b128.
__device__ __forceinline__ int swzHV(int row, int col) { return (row * 384 + col) ^ ((row & 7) << 3); }
__device__ __forceinline__ int swzHE(int row, int col) { return (row * 128 + col) ^ ((row & 7) << 3); }

__global__ void detect_mask_kernel(const unsigned int* __restrict__ m, int* __restrict__ flag) {
    int i = blockIdx.x * 256 + threadIdx.x;
    if (i < 4096 && m[i] > 1u) atomicOr(flag, 1);
}

// Pack weights into MFMA B-fragment order (bf16 hi/lo split). Same layouts as round 2.
__global__ void prep_kernel(
    const float* __restrict__ Wih_v2e, const float* __restrict__ Whh_v2e,
    const float* __restrict__ bih_v2e, const float* __restrict__ bhh_v2e,
    const float* __restrict__ Wih_e2v, const float* __restrict__ Whh_e2v,
    const float* __restrict__ bih_e2v, const float* __restrict__ bhh_e2v,
    const float* __restrict__ out_w,
    u16* __restrict__ WvFh, u16* __restrict__ WvFl,
    u16* __restrict__ WeFh, u16* __restrict__ WeFl,
    u16* __restrict__ OwFh, u16* __restrict__ OwFl,
    float* __restrict__ bv, float* __restrict__ be)
{
    int idx = blockIdx.x * 256 + threadIdx.x;
    if (idx < 262144) {
        const int r = idx & 7, l = (idx >> 3) & 63, t = idx >> 9;
        const int kk = t & 15, nt = t >> 4;
        const int j = nt * 16 + (l & 15);
        const int k = kk * 32 + (l >> 4) * 8 + r;
        const float w = (k < 384) ? Wih_v2e[j * 384 + k] : Whh_v2e[j * 128 + (k - 384)];
        const u16 h = f2bf(w);
        WvFh[idx] = h; WvFl[idx] = f2bf(w - bf2f(h));
        return;
    }
    idx -= 262144;
    if (idx < 393216) {
        const int r = idx & 7, l = (idx >> 3) & 63, t = idx >> 9;  // t < 768
        const int kk = t & 7, nt = (t >> 3) & 31, p = t >> 8;
        const int j = nt * 16 + (l & 15);
        const int k = kk * 32 + (l >> 4) * 8 + r;
        const float w = (k < 128) ? Wih_e2v[(p * 512 + j) * 128 + k]
                                  : Whh_e2v[(p * 512 + j) * 128 + (k - 128)];
        const u16 h = f2bf(w);
        WeFh[idx] = h; WeFl[idx] = f2bf(w - bf2f(h));
        return;
    }
    idx -= 393216;
    if (idx < 256000) {
        const int r = idx & 7, l = (idx >> 3) & 63, t = idx >> 9;  // t < 500
        const int kk = t & 3, nt = t >> 2;
        const int j = nt * 16 + (l & 15);
        const int k = kk * 32 + (l >> 4) * 8 + r;
        const float w = out_w[j * 128 + k];
        const u16 h = f2bf(w);
        OwFh[idx] = h; OwFl[idx] = f2bf(w - bf2f(h));
        return;
    }
    idx -= 256000;
    if (idx < 512) { bv[idx] = bih_v2e[idx] + bhh_v2e[idx]; return; }
    idx -= 512;
    if (idx < 1536) { be[idx] = bih_e2v[idx] + bhh_e2v[idx]; return; }
}

// Persistent fused kernel: block = 512 threads (8 waves) owns 64 edges for all 6 iterations.
// LDS: h_v hi/lo [64][384] + h_e hi/lo [64][128] (XOR-swizzled). c_v/c_e in registers.
// Wave w owns gate-dim slice d = w*16 + lr for all 4 gates (disjoint B columns -> B read once/block).
__global__ __launch_bounds__(512, 2) void fused_kernel(
    const int* __restrict__ x_v,
    const float* __restrict__ emb,
    const float* __restrict__ eiw, const float* __restrict__ eib,
    const u16* __restrict__ WvFh, const u16* __restrict__ WvFl,
    const u16* __restrict__ WeFh, const u16* __restrict__ WeFl,
    const float* __restrict__ bv, const float* __restrict__ be,
    const void* __restrict__ mask, const int* __restrict__ flagp,
    u16* __restrict__ hvOutH, u16* __restrict__ hvOutL)
{
    extern __shared__ u16 lds[];
    u16* HVh = lds;                // 24576 u16
    u16* HVl = lds + 24576;        // 24576
    u16* HEh = lds + 49152;        // 8192
    u16* HEl = lds + 57344;        // 8192  -> 131072 B total

    const int tid = threadIdx.x;
    const int w = tid >> 6, l = tid & 63;
    const int lr = l & 15, lk = l >> 4;
    const int e0 = blockIdx.x * 64;

    // ---- init h_v from embeddings (split hi/lo into LDS)
    for (int i = tid; i < 64 * 48; i += 512) {
        const int row = i / 48, seg = i % 48;
        const int col0 = seg * 8;
        int id = x_v[(e0 + row) * 3 + (col0 >> 7)];
        if (id < 0 || id > VOCAB_) id = VOCAB_;
        const float* s = emb + id * D_ + (col0 & 127);
        float4 a = *(const float4*)s, b = *(const float4*)(s + 4);
        float xs[8] = {a.x, a.y, a.z, a.w, b.x, b.y, b.z, b.w};
        u16x8 H, L;
        #pragma unroll
        for (int j = 0; j < 8; ++j) { H[j] = f2bf(xs[j]); L[j] = f2bf(xs[j] - bf2f(H[j])); }
        const int si = swzHV(row, col0);
        *(u16x8*)&HVh[si] = H;
        *(u16x8*)&HVl[si] = L;
    }
    // ---- init h_e (same vector for every edge)
    for (int i = tid; i < 64 * 16; i += 512) {
        const int row = i / 16, col0 = (i % 16) * 8;
        u16x8 H, L;
        #pragma unroll
        for (int j = 0; j < 8; ++j) {
            const float x = eiw[col0 + j] + eib[col0 + j];
            H[j] = f2bf(x); L[j] = f2bf(x - bf2f(H[j]));
        }
        const int si = swzHE(row, col0);
        *(u16x8*)&HEh[si] = H;
        *(u16x8*)&HEl[si] = L;
    }

    // ---- per-lane constants: mask bits, biases, c-state
    const int isByte = *flagp;
    unsigned mbits[3];
    #pragma unroll
    for (int p = 0; p < 3; ++p) {
        unsigned mb = 0;
        #pragma unroll
        for (int mt = 0; mt < 4; ++mt)
            #pragma unroll
            for (int r = 0; r < 4; ++r) {
                const int v = (e0 + mt * 16 + lk * 4 + r) * 3 + p;
                const bool m = isByte ? (((const unsigned char*)mask)[v] != 0)
                                      : (((const int*)mask)[v] != 0);
                mb |= (unsigned)m << (mt * 4 + r);
            }
        mbits[p] = mb;
    }
    const int d = w * 16 + lr;
    const float bvi = bv[d], bvf = bv[128 + d], bvg = bv[256 + d], bvo = bv[384 + d];
    float bei[3], bef[3], beg[3], beo[3];
    #pragma unroll
    for (int p = 0; p < 3; ++p) {
        bei[p] = be[p * 512 + d];       bef[p] = be[p * 512 + 128 + d];
        beg[p] = be[p * 512 + 256 + d]; beo[p] = be[p * 512 + 384 + d];
    }
    float ce[4][4], cv[3][4][4];
    #pragma unroll
    for (int mt = 0; mt < 4; ++mt)
        #pragma unroll
        for (int r = 0; r < 4; ++r) {
            ce[mt][r] = 0.0f;
            #pragma unroll
            for (int p = 0; p < 3; ++p) cv[p][mt][r] = 0.0f;
        }

    __syncthreads();

#define GEMM_STEP(WH, WL, FBASE)                                         \
    { _Pragma("unroll")                                                  \
      for (int g = 0; g < 4; ++g) {                                      \
          const int fb = (FBASE);                                        \
          bf16x8 Bh = ld8(WH + fb), Bl = ld8(WL + fb);                   \
          _Pragma("unroll")                                              \
          for (int mt = 0; mt < 4; ++mt) {                               \
              acc[mt][g] = MF(Ah[mt], Bh, acc[mt][g]);                   \
              acc[mt][g] = MF(Ah[mt], Bl, acc[mt][g]);                   \
              acc[mt][g] = MF(Al[mt], Bh, acc[mt][g]);                   \
          }                                                              \
      } }

    for (int it = 0; it < ITERS_; ++it) {
        // ======== vertex -> edge ========
        {
            f32x4 acc[4][4];
            #pragma unroll
            for (int mt = 0; mt < 4; ++mt)
                #pragma unroll
                for (int g = 0; g < 4; ++g) acc[mt][g] = (f32x4)0.0f;

            #pragma unroll 2
            for (int kk = 0; kk < 12; ++kk) {
                bf16x8 Ah[4], Al[4];
                #pragma unroll
                for (int mt = 0; mt < 4; ++mt) {
                    const int si = swzHV(mt * 16 + lr, kk * 32 + lk * 8);
                    Ah[mt] = ld8(HVh + si); Al[mt] = ld8(HVl + si);
                }
                GEMM_STEP(WvFh, WvFl, (((g * 8 + w) * 16 + kk) * 64 + l) * 8)
            }
            #pragma unroll 2
            for (int kk = 12; kk < 16; ++kk) {
                bf16x8 Ah[4], Al[4];
                #pragma unroll
                for (int mt = 0; mt < 4; ++mt) {
                    const int si = swzHE(mt * 16 + lr, (kk - 12) * 32 + lk * 8);
                    Ah[mt] = ld8(HEh + si); Al[mt] = ld8(HEl + si);
                }
                GEMM_STEP(WvFh, WvFl, (((g * 8 + w) * 16 + kk) * 64 + l) * 8)
            }
            __syncthreads();   // all HE reads done before HE writes
            #pragma unroll
            for (int mt = 0; mt < 4; ++mt)
                #pragma unroll
                for (int r = 0; r < 4; ++r) {
                    const int row = mt * 16 + lk * 4 + r;
                    float gi = sigmoid_f(acc[mt][0][r] + bvi);
                    float gf = sigmoid_f(acc[mt][1][r] + bvf);
                    float gg = tanh_f(acc[mt][2][r] + bvg);
                    float go = sigmoid_f(acc[mt][3][r] + bvo);
                    float cn = gf * ce[mt][r] + gi * gg;
                    ce[mt][r] = cn;
                    float hn = go * tanh_f(cn);
                    u16 hh = f2bf(hn);
                    const int si = swzHE(row, d);
                    HEh[si] = hh; HEl[si] = f2bf(hn - bf2f(hh));
                }
            __syncthreads();   // HE complete before e2v reads
        }
        // ======== edge -> vertex (3 position-specific LSTMs) ========
        #pragma unroll
        for (int p = 0; p < 3; ++p) {
            f32x4 acc[4][4];
            #pragma unroll
            for (int mt = 0; mt < 4; ++mt)
                #pragma unroll
                for (int g = 0; g < 4; ++g) acc[mt][g] = (f32x4)0.0f;

            #pragma unroll 2
            for (int kk = 0; kk < 4; ++kk) {
                bf16x8 Ah[4], Al[4];
                #pragma unroll
                for (int mt = 0; mt < 4; ++mt) {
                    const int si = swzHE(mt * 16 + lr, kk * 32 + lk * 8);
                    Ah[mt] = ld8(HEh + si); Al[mt] = ld8(HEl + si);
                }
                GEMM_STEP(WeFh, WeFl, ((((p * 32) + (g * 8 + w)) * 8 + kk) * 64 + l) * 8)
            }
            #pragma unroll 2
            for (int kk = 4; kk < 8; ++kk) {
                bf16x8 Ah[4], Al[4];
                #pragma unroll
                for (int mt = 0; mt < 4; ++mt) {
                    const int si = swzHV(mt * 16 + lr, p * 128 + (kk - 4) * 32 + lk * 8);
                    Ah[mt] = ld8(HVh + si); Al[mt] = ld8(HVl + si);
                }
                GEMM_STEP(WeFh, WeFl, ((((p * 32) + (g * 8 + w)) * 8 + kk) * 64 + l) * 8)
            }
            __syncthreads();   // all HV[p] reads done before HV[p] writes
            #pragma unroll
            for (int mt = 0; mt < 4; ++mt)
                #pragma unroll
                for (int r = 0; r < 4; ++r) {
                    if ((mbits[p] >> (mt * 4 + r)) & 1u) {
                        const int row = mt * 16 + lk * 4 + r;
                        float gi = sigmoid_f(acc[mt][0][r] + bei[p]);
                        float gf = sigmoid_f(acc[mt][1][r] + bef[p]);
                        float gg = tanh_f(acc[mt][2][r] + beg[p]);
                        float go = sigmoid_f(acc[mt][3][r] + beo[p]);
                        float cn = gf * cv[p][mt][r] + gi * gg;
                        cv[p][mt][r] = cn;
                        float hn = go * tanh_f(cn);
                        u16 hh = f2bf(hn);
                        const int si = swzHV(row, p * 128 + d);
                        HVh[si] = hh; HVl[si] = f2bf(hn - bf2f(hh));
                    }
                }
            // no barrier needed between cell(p) and MFMA(p+1): disjoint LDS regions
        }
        __syncthreads();       // HV[2] writes complete before next v2e (or copy-out)
    }

    // ---- write final h_v (hi/lo) for the projection kernel: [vertex][128] row-major
    for (int i = tid; i < 64 * 48; i += 512) {
        const int row = i / 48, col0 = (i % 48) * 8;
        const int si = swzHV(row, col0);
        const size_t go = (size_t)(e0 + row) * 384 + col0;
        *(u16x8*)&hvOutH[go] = *(const u16x8*)&HVh[si];
        *(u16x8*)&hvOutL[go] = *(const u16x8*)&HVl[si];
    }
#undef GEMM_STEP
}

// logits = h_v @ out_w^T + out_b.  Wave: 32 rows in-register, loops 125 N-tiles.
__global__ __launch_bounds__(256) void proj_kernel(
    const u16* __restrict__ hvh, const u16* __restrict__ hvl,
    const u16* __restrict__ WFh, const u16* __restrict__ WFl,
    const float* __restrict__ out_b, float* __restrict__ out)
{
    const int tid = threadIdx.x, l = tid & 63;
    const int wid = blockIdx.x * 4 + (tid >> 6);   // 0..3071
    const int r0 = wid * 32;
    const int lr = l & 15, lk = l >> 4;

    bf16x8 Ah[2][4], Al[2][4];
    #pragma unroll
    for (int mt = 0; mt < 2; ++mt)
        #pragma unroll
        for (int kk = 0; kk < 4; ++kk) {
            const int off = (r0 + mt * 16 + lr) * D_ + kk * 32 + lk * 8;
            Ah[mt][kk] = ld8(hvh + off);
            Al[mt][kk] = ld8(hvl + off);
        }

    for (int nt = 0; nt < 125; ++nt) {
        f32x4 a0 = (f32x4)0.0f, a1 = (f32x4)0.0f;
        #pragma unroll
        for (int kk = 0; kk < 4; ++kk) {
            const int fb = ((nt * 4 + kk) * 64 + l) * 8;
            bf16x8 Bh = ld8(WFh + fb), Bl = ld8(WFl + fb);
            a0 = MF(Ah[0][kk], Bh, a0); a0 = MF(Ah[0][kk], Bl, a0); a0 = MF(Al[0][kk], Bh, a0);
            a1 = MF(Ah[1][kk], Bh, a1); a1 = MF(Ah[1][kk], Bl, a1); a1 = MF(Al[1][kk], Bh, a1);
        }
        const int n = nt * 16 + lr;
        const float bb = out_b[n];
        #pragma unroll
        for (int r = 0; r < 4; ++r) {
            const size_t row = (size_t)(r0 + lk * 4 + r);
            out[row * VOCAB_ + n] = a0[r] + bb;
            out[(row + 16) * VOCAB_ + n] = a1[r] + bb;
        }
    }
}

extern "C" void kernel_launch(void* const* d_in, const int* in_sizes, int n_in,
                              void* d_out, int out_size, void* d_ws, size_t ws_size,
                              hipStream_t stream)
{
    const int*   x_v     = (const int*)  d_in[0];
    const void*  mask    = d_in[1];
    const float* emb     = (const float*)d_in[2];
    const float* eiw     = (const float*)d_in[3];
    const float* eib     = (const float*)d_in[4];
    const float* Wih_v2e = (const float*)d_in[5];
    const float* Whh_v2e = (const float*)d_in[6];
    const float* bih_v2e = (const float*)d_in[7];
    const float* bhh_v2e = (const float*)d_in[8];
    const float* Wih_e2v = (const float*)d_in[9];
    const float* Whh_e2v = (const float*)d_in[10];
    const float* bih_e2v = (const float*)d_in[11];
    const float* bhh_e2v = (const float*)d_in[12];
    const float* out_w   = (const float*)d_in[13];
    const float* out_b   = (const float*)d_in[14];
    float* out = (float*)d_out;

    // d_ws carve (~54 MB; ws_size >= 71 MB verified in round 2)
    char* ws = (char*)d_ws;
    u16* hvh  = (u16*)(ws);
    u16* hvl  = (u16*)(ws + 25165824);
    u16* WvFh = (u16*)(ws + 50331648);
    u16* WvFl = (u16*)(ws + 50855936);
    u16* WeFh = (u16*)(ws + 51380224);
    u16* WeFl = (u16*)(ws + 52166656);
    u16* OwFh = (u16*)(ws + 52953088);
    u16* OwFl = (u16*)(ws + 53465088);
    float* bv = (float*)(ws + 53977088);
    float* be = (float*)(ws + 53979136);
    int* flag = (int*)(ws + 53985280);

    hipFuncSetAttribute(reinterpret_cast<const void*>(fused_kernel),
                        hipFuncAttributeMaxDynamicSharedMemorySize, 131072);

    hipMemsetAsync(flag, 0, 4, stream);
    detect_mask_kernel<<<16, 256, 0, stream>>>((const unsigned int*)mask, flag);
    prep_kernel<<<3568, 256, 0, stream>>>(Wih_v2e, Whh_v2e, bih_v2e, bhh_v2e,
                                          Wih_e2v, Whh_e2v, bih_e2v, bhh_e2v, out_w,
                                          WvFh, WvFl, WeFh, WeFl, OwFh, OwFl, bv, be);
    fused_kernel<<<E_CNT / 64, 512, 131072, stream>>>(x_v, emb, eiw, eib,
                                                      WvFh, WvFl, WeFh, WeFl, bv, be,
                                                      mask, flag, hvh, hvl);
    proj_kernel<<<768, 256, 0, stream>>>(hvh, hvl, OwFh, OwFl, out_b, out);
}